// Round 10
// baseline (132.321 us; speedup 1.0000x reference)
//
#include <hip/hip_runtime.h>

#define N_PART 2048
#define NP_OBJ 2000
#define NREL 16384

typedef unsigned short u16;
typedef __attribute__((ext_vector_type(8))) short bf16x8;
typedef __attribute__((ext_vector_type(4))) float f32x4;
typedef __attribute__((ext_vector_type(4))) unsigned int u32x4;

__device__ __forceinline__ int clampi(int v) {
  return v < 0 ? 0 : (v >= N_PART ? N_PART - 1 : v);
}
__device__ __forceinline__ u16 f2b(float f) {
  union { float f; unsigned int u; } v; v.f = f;
  return (u16)((v.u + 0x7fffu + ((v.u >> 16) & 1u)) >> 16);  // RNE
}
__device__ __forceinline__ float b2f(u16 u) {
  union { unsigned int i; float f; } v; v.i = ((unsigned int)u) << 16; return v.f;
}

struct TWSeg { const float* src; u16* dst; int K; int Kp; };
struct TW10 { TWSeg s[10]; };

// ---- front kernel: extract (nt loads) + weight transpose + pinputs + agg zero
#define NB_EXT 8192
#define NB_TW  320
#define NB_PIN 8
#define NB_AGZ 8
__global__ __launch_bounds__(256) void k_front(
    const float* __restrict__ Rr, const float* __restrict__ Rs,
    int* __restrict__ recv /* send = recv + NREL */, TW10 tw,
    const float* __restrict__ state, const float* __restrict__ attrs,
    const float* __restrict__ action, const float* __restrict__ phys,
    float* __restrict__ pin, float* __restrict__ agg) {
  int b = blockIdx.x;
  int tid = threadIdx.x;
  if (b < NB_EXT) {
    // ---- one-hot extraction: one wave per row, non-temporal batched loads ----
    int wid = b * 4 + (tid >> 6);          // 0 .. 2*NREL-1
    int lane = tid & 63;
    bool second = wid >= NREL;
    int row = second ? wid - NREL : wid;
    const u32x4* p = (const u32x4*)((second ? Rs : Rr) + (size_t)row * N_PART) + lane;
    u32x4 v[8];
#pragma unroll
    for (int k = 0; k < 8; ++k) v[k] = __builtin_nontemporal_load(&p[k * 64]);
    int col = 0;
#pragma unroll
    for (int k = 0; k < 8; ++k) {
      int base = (k * 64 + lane) * 4;
      if (v[k].x) col = base;        // v_cmp + v_cndmask, branchless
      if (v[k].y) col = base + 1;
      if (v[k].z) col = base + 2;
      if (v[k].w) col = base + 3;
    }
#pragma unroll
    for (int s = 32; s; s >>= 1) col |= __shfl_xor(col, s);
    if (lane == 0) recv[(second ? NREL : 0) + row] = col;
  } else if (b < NB_EXT + NB_TW) {
    // ---- weight transpose + bf16 convert: W[K][128] -> WT[128][Kp] ----
    int b2 = b - NB_EXT;
    TWSeg sg = tw.s[b2 >> 5];
    int n = (b2 & 31) * 4 + (tid >> 6);
    int k0 = tid & 63;
    for (int k = k0; k < sg.Kp; k += 64) {
      float v = (k < sg.K) ? sg.src[(size_t)k * 128 + n] : 0.f;
      sg.dst[(size_t)n * sg.Kp + k] = f2b(v);
    }
  } else if (b < NB_EXT + NB_TW + NB_PIN) {
    // ---- p_inputs [2048][16] ----
    int i = (b - NB_EXT - NB_TW) * 256 + tid;
    float s0[3], s1[3], s2[3];
#pragma unroll
    for (int d = 0; d < 3; ++d) {
      s0[d] = state[(0 * N_PART + i) * 3 + d];
      s1[d] = state[(1 * N_PART + i) * 3 + d];
      s2[d] = state[(2 * N_PART + i) * 3 + d];
    }
    float* o = pin + (size_t)i * 16;
    o[0] = attrs[i * 2 + 0];
    o[1] = attrs[i * 2 + 1];
#pragma unroll
    for (int d = 0; d < 3; ++d) {
      o[2 + d] = s1[d] - s0[d];
      o[5 + d] = s2[d] - s1[d];
      o[8 + d] = s2[d];
    }
    o[11] = (i < NP_OBJ) ? phys[i] : 0.f;
#pragma unroll
    for (int d = 0; d < 3; ++d) o[12 + d] = action[i * 3 + d];
    o[15] = 0.f;
  } else {
    // ---- zero agg (N_PART*128 floats = 65536 float4) ----
    int b3 = b - NB_EXT - NB_TW - NB_PIN;
    float4* a4 = (float4*)agg;
    float4 z = make_float4(0.f, 0.f, 0.f, 0.f);
#pragma unroll
    for (int j = 0; j < 32; ++j) a4[(size_t)j * 2048 + b3 * 256 + tid] = z;
  }
}

// ---- one MFMA MLP layer on a 64-row LDS-resident tile --------------------
template <int K, bool TOGLOBAL>
__device__ __forceinline__ void re_layer(
    const u16 (*hIn)[136], u16 (*hOut)[136], u16 (*wt)[72],
    const u16* __restrict__ WTg, const float* __restrict__ bias,
    u16* __restrict__ gout, int row0, int tid) {
  int lane = tid & 63, w = tid >> 6;
  int wr0 = (w >> 1) * 32, wc0 = (w & 1) * 64;
  f32x4 acc[2][4] = {};
  for (int kc = 0; kc < K; kc += 64) {
    __syncthreads();
#pragma unroll
    for (int i = 0; i < 4; ++i) {
      int idx = i * 256 + tid;
      int n = idx >> 3, kl8 = (idx & 7) * 8;
      *(bf16x8*)&wt[n][kl8] = *(const bf16x8*)&WTg[(size_t)n * K + kc + kl8];
    }
    __syncthreads();
#pragma unroll
    for (int ks = 0; ks < 64; ks += 32) {
      bf16x8 a0 = *(const bf16x8*)&hIn[wr0 + (lane & 15)][kc + ks + 8 * (lane >> 4)];
      bf16x8 a1 = *(const bf16x8*)&hIn[wr0 + 16 + (lane & 15)][kc + ks + 8 * (lane >> 4)];
#pragma unroll
      for (int ct = 0; ct < 4; ++ct) {
        bf16x8 bq = *(const bf16x8*)&wt[wc0 + ct * 16 + (lane & 15)][ks + 8 * (lane >> 4)];
        acc[0][ct] = __builtin_amdgcn_mfma_f32_16x16x32_bf16(a0, bq, acc[0][ct], 0, 0, 0);
        acc[1][ct] = __builtin_amdgcn_mfma_f32_16x16x32_bf16(a1, bq, acc[1][ct], 0, 0, 0);
      }
    }
  }
  __syncthreads();
#pragma unroll
  for (int ct = 0; ct < 4; ++ct) {
    int col = wc0 + ct * 16 + (lane & 15);
    float bb = bias[col];
#pragma unroll
    for (int rt = 0; rt < 2; ++rt) {
#pragma unroll
      for (int rg = 0; rg < 4; ++rg) {
        int rl = wr0 + rt * 16 + (lane >> 4) * 4 + rg;
        float v = fmaxf(acc[rt][ct][rg] + bb, 0.f);
        if (TOGLOBAL) gout[(size_t)(row0 + rl) * 128 + col] = f2b(v);
        else          hOut[rl][col] = f2b(v);
      }
    }
  }
}

// ---- fused encoders: blocks [0,256) relation rows, [256,288) particle rows
__global__ __launch_bounds__(256) void k_enc(
    const float* __restrict__ pin, const int* __restrict__ recv,
    const int* __restrict__ send, const float* __restrict__ pinst,
    const u16* __restrict__ rw0T, const float* __restrict__ rb0,
    const u16* __restrict__ rw1T, const float* __restrict__ rb1,
    const u16* __restrict__ rw2T, const float* __restrict__ rb2,
    const u16* __restrict__ pw0T, const float* __restrict__ pb0,
    const u16* __restrict__ pw1T, const float* __restrict__ pb1,
    const u16* __restrict__ pw2T, const float* __restrict__ pb2,
    u16* __restrict__ RE, u16* __restrict__ PE) {
  __shared__ u16 hA[64][136];
  __shared__ u16 hB[64][136];
  __shared__ u16 wt[128][72];
  int tid = threadIdx.x;
  bool isRel = blockIdx.x < NREL / 64;
  int row0 = (isRel ? blockIdx.x : blockIdx.x - NREL / 64) * 64;
  if (isRel) {
#pragma unroll
    for (int i = 0; i < 16; ++i) {
      int idx = i * 256 + tid;
      int r = idx >> 6, c = idx & 63;
      int e = row0 + r;
      int rr = clampi(recv[e]), ss = clampi(send[e]);
      const float* pr = pin + (size_t)rr * 16;
      const float* ps = pin + (size_t)ss * 16;
      float v = 0.f;
      if (c < 15) v = pr[c];
      else if (c < 30) v = ps[c - 15];
      else if (c < 32) v = pr[c - 30];
      else if (c < 34) v = ps[c - 32];
      else if (c == 34) {
        float gd = 0.f;
#pragma unroll
        for (int j = 0; j < 8; ++j) {
          float gr = (rr < NP_OBJ) ? pinst[rr * 8 + j] : 0.f;
          float gs = (ss < NP_OBJ) ? pinst[ss * 8 + j] : 0.f;
          gd += fabsf(gr - gs);
        }
        v = gd;
      } else if (c < 44) {
        v = pr[2 + c - 35] - ps[2 + c - 35];
      }
      hA[r][c] = f2b(v);
    }
  } else {
#pragma unroll
    for (int i = 0; i < 16; ++i) {
      int idx = i * 256 + tid;
      int r = idx >> 6, c = idx & 63;
      float v = (c < 16) ? pin[(size_t)(row0 + r) * 16 + c] : 0.f;
      hA[r][c] = f2b(v);
    }
  }
  const u16* w0T = isRel ? rw0T : pw0T;  const float* b0 = isRel ? rb0 : pb0;
  const u16* w1T = isRel ? rw1T : pw1T;  const float* b1 = isRel ? rb1 : pb1;
  const u16* w2T = isRel ? rw2T : pw2T;  const float* b2 = isRel ? rb2 : pb2;
  u16* gout = isRel ? RE : PE;
  re_layer<64, false>(hA, hB, wt, w0T, b0, nullptr, row0, tid);
  re_layer<128, false>(hB, hA, wt, w1T, b1, nullptr, row0, tid);
  re_layer<128, true>(hA, hB, wt, w2T, b2, gout, row0, tid);
}

// ---- MFMA GEMM, 32-row tiles ---------------------------------------------
// MODE 1 (KTOT=384): A row e = [RE[e] | eff[recv[e]] | eff[send[e]]];
//          epilogue relu + atomic scatter-add into aggOut[recv[e]].
// MODE 2 (KTOT=256): A row i = [PE[i] | aggIn[i](f32)]; stager zeroes aggIn
//          after read (self-clean); epilogue relu(+bias+resid)->bf16.
template <int MODE, int KTOT>
__global__ __launch_bounds__(256) void k_mgemm32(
    const u16* __restrict__ A, const u16* __restrict__ WT,
    const float* __restrict__ bias,
    const u16* __restrict__ resid, u16* __restrict__ out,
    const u16* __restrict__ eff, float* __restrict__ aggIn,
    const int* __restrict__ recv, const int* __restrict__ send,
    float* __restrict__ aggOut) {
  __shared__ u16 a_lds[32][72];
  __shared__ u16 wt_lds[128][72];
  int tid = threadIdx.x;
  int lane = tid & 63, w = tid >> 6;
  int wr0 = (w >> 1) * 16, wc0 = (w & 1) * 64;
  int row0 = blockIdx.x * 32;
  f32x4 acc[4] = {};
  for (int kc = 0; kc < KTOT; kc += 64) {
    __syncthreads();
    {
      int r = tid >> 3, kl8 = (tid & 7) * 8;
      int grow = row0 + r;
      if (MODE == 1) {
        const u16* src;
        if (kc < 128)      src = A + (size_t)grow * 128 + kc;
        else if (kc < 256) src = eff + (size_t)clampi(recv[grow]) * 128 + (kc - 128);
        else               src = eff + (size_t)clampi(send[grow]) * 128 + (kc - 256);
        *(bf16x8*)&a_lds[r][kl8] = *(const bf16x8*)&src[kl8];
      } else {
        if (kc < 128) {
          *(bf16x8*)&a_lds[r][kl8] = *(const bf16x8*)&A[(size_t)grow * 128 + kc + kl8];
        } else {
          float* fs = aggIn + (size_t)grow * 128 + (kc - 128) + kl8;
          float4 v0 = *(const float4*)&fs[0];
          float4 v1 = *(const float4*)&fs[4];
          bf16x8 t;
          t[0] = (short)f2b(v0.x); t[1] = (short)f2b(v0.y);
          t[2] = (short)f2b(v0.z); t[3] = (short)f2b(v0.w);
          t[4] = (short)f2b(v1.x); t[5] = (short)f2b(v1.y);
          t[6] = (short)f2b(v1.z); t[7] = (short)f2b(v1.w);
          *(bf16x8*)&a_lds[r][kl8] = t;
          float4 z = make_float4(0.f, 0.f, 0.f, 0.f);
          *(float4*)&fs[0] = z;  // self-clean agg for next step
          *(float4*)&fs[4] = z;
        }
      }
    }
#pragma unroll
    for (int i = 0; i < 4; ++i) {
      int idx = i * 256 + tid;
      int n = idx >> 3, kl8 = (idx & 7) * 8;
      *(bf16x8*)&wt_lds[n][kl8] = *(const bf16x8*)&WT[(size_t)n * KTOT + kc + kl8];
    }
    __syncthreads();
#pragma unroll
    for (int ks = 0; ks < 64; ks += 32) {
      bf16x8 a0 = *(const bf16x8*)&a_lds[wr0 + (lane & 15)][ks + 8 * (lane >> 4)];
#pragma unroll
      for (int ct = 0; ct < 4; ++ct) {
        bf16x8 bq = *(const bf16x8*)&wt_lds[wc0 + ct * 16 + (lane & 15)][ks + 8 * (lane >> 4)];
        acc[ct] = __builtin_amdgcn_mfma_f32_16x16x32_bf16(a0, bq, acc[ct], 0, 0, 0);
      }
    }
  }
  int rbase = row0 + wr0 + (lane >> 4) * 4;
  int dst[4];
#pragma unroll
  for (int rg = 0; rg < 4; ++rg)
    dst[rg] = (MODE == 1) ? clampi(recv[rbase + rg]) : 0;
#pragma unroll
  for (int ct = 0; ct < 4; ++ct) {
    int col = wc0 + ct * 16 + (lane & 15);
    float bb = bias[col];
#pragma unroll
    for (int rg = 0; rg < 4; ++rg) {
      int row = rbase + rg;
      float v = acc[ct][rg] + bb;
      if (MODE == 1) {
        v = fmaxf(v, 0.f);
        atomicAdd(&aggOut[(size_t)dst[rg] * 128 + col], v);
      } else {
        v += b2f(resid[(size_t)row * 128 + col]);
        v = fmaxf(v, 0.f);
        out[(size_t)row * 128 + col] = f2b(v);
      }
    }
  }
}

// ---- fused predictor: 2 MFMA layers + 3-col GEMV + clip + outputs --------
__global__ __launch_bounds__(256) void k_np(
    const u16* __restrict__ eff,
    const u16* __restrict__ w0T, const float* __restrict__ b0,
    const u16* __restrict__ w1T, const float* __restrict__ b1,
    const float* __restrict__ w2, const float* __restrict__ b2,
    const float* __restrict__ state, float* __restrict__ out) {
  __shared__ u16 hA[64][136];
  __shared__ u16 hB[64][136];
  __shared__ u16 wt[128][72];
  __shared__ float sw2[384];
  int tid = threadIdx.x;
  int row0 = blockIdx.x * 64;
#pragma unroll
  for (int i = 0; i < 4; ++i) {
    int idx = i * 256 + tid;
    int r = idx >> 4, kl8 = (idx & 15) * 8;
    *(bf16x8*)&hA[r][kl8] = *(const bf16x8*)&eff[(size_t)(row0 + r) * 128 + kl8];
  }
  for (int j = tid; j < 384; j += 256) sw2[j] = w2[j];
  re_layer<128, false>(hA, hB, wt, w0T, b0, nullptr, row0, tid);
  re_layer<128, false>(hB, hA, wt, w1T, b1, nullptr, row0, tid);
  __syncthreads();
  int r = tid >> 2, d = tid & 3;
  if (d < 3) {
    int row = row0 + r;
    if (row < NP_OBJ) {
      float acc = b2[d];
#pragma unroll 8
      for (int k = 0; k < 128; ++k) acc += b2f(hA[r][k]) * sw2[k * 3 + d];
      float cl = fminf(fmaxf(acc, -100.f), 100.f);
      out[row * 3 + d] = state[(size_t)(2 * N_PART + row) * 3 + d] + cl;
      out[NP_OBJ * 3 + row * 3 + d] = acc;
    }
  }
}

extern "C" void kernel_launch(void* const* d_in, const int* in_sizes, int n_in,
                              void* d_out, int out_size, void* d_ws, size_t ws_size,
                              hipStream_t stream) {
  const float* state  = (const float*)d_in[0];
  const float* attrs  = (const float*)d_in[1];
  const float* Rr     = (const float*)d_in[2];
  const float* Rs     = (const float*)d_in[3];
  const float* pinst  = (const float*)d_in[4];
  const float* action = (const float*)d_in[5];
  const float* phys   = (const float*)d_in[6];
  const float* pe_w0 = (const float*)d_in[7];  const float* pe_b0 = (const float*)d_in[8];
  const float* pe_w1 = (const float*)d_in[9];  const float* pe_b1 = (const float*)d_in[10];
  const float* pe_w2 = (const float*)d_in[11]; const float* pe_b2 = (const float*)d_in[12];
  const float* re_w0 = (const float*)d_in[13]; const float* re_b0 = (const float*)d_in[14];
  const float* re_w1 = (const float*)d_in[15]; const float* re_b1 = (const float*)d_in[16];
  const float* re_w2 = (const float*)d_in[17]; const float* re_b2 = (const float*)d_in[18];
  const float* pp_w  = (const float*)d_in[19]; const float* pp_b  = (const float*)d_in[20];
  const float* rp_w  = (const float*)d_in[21]; const float* rp_b  = (const float*)d_in[22];
  const float* np_w0 = (const float*)d_in[23]; const float* np_b0 = (const float*)d_in[24];
  const float* np_w1 = (const float*)d_in[25]; const float* np_b1 = (const float*)d_in[26];
  const float* np_w2 = (const float*)d_in[27]; const float* np_b2 = (const float*)d_in[28];

  char* ws = (char*)d_ws;
  size_t off = 0;
  auto alloc = [&](size_t b) { size_t o = off; off += (b + 255) & ~(size_t)255; return o; };
  int* recv = (int*)(ws + alloc(2 * NREL * 4));  // send follows recv
  int* send = recv + NREL;
  float* pin = (float*)(ws + alloc((size_t)N_PART * 16 * 4));
  u16* PE  = (u16*)(ws + alloc((size_t)N_PART * 128 * 2));
  u16* RE  = (u16*)(ws + alloc((size_t)NREL * 128 * 2));
  float* agg = (float*)(ws + alloc((size_t)N_PART * 128 * 4));
  u16* eA  = (u16*)(ws + alloc((size_t)N_PART * 128 * 2));
  u16* eB  = (u16*)(ws + alloc((size_t)N_PART * 128 * 2));
  u16* re_w0T = (u16*)(ws + alloc(128 * 64 * 2));
  u16* re_w1T = (u16*)(ws + alloc(128 * 128 * 2));
  u16* re_w2T = (u16*)(ws + alloc(128 * 128 * 2));
  u16* rp_wT  = (u16*)(ws + alloc(128 * 384 * 2));
  u16* pp_wT  = (u16*)(ws + alloc(128 * 256 * 2));
  u16* pe_w0T = (u16*)(ws + alloc(128 * 64 * 2));
  u16* pe_w1T = (u16*)(ws + alloc(128 * 128 * 2));
  u16* pe_w2T = (u16*)(ws + alloc(128 * 128 * 2));
  u16* np_w0T = (u16*)(ws + alloc(128 * 128 * 2));
  u16* np_w1T = (u16*)(ws + alloc(128 * 128 * 2));
  if (off > ws_size) return;  // diagnostic guard

  TW10 tw;
  tw.s[0] = {re_w0, re_w0T, 44, 64};
  tw.s[1] = {re_w1, re_w1T, 128, 128};
  tw.s[2] = {re_w2, re_w2T, 128, 128};
  tw.s[3] = {rp_w,  rp_wT,  384, 384};
  tw.s[4] = {pp_w,  pp_wT,  256, 256};
  tw.s[5] = {pe_w0, pe_w0T, 15, 64};
  tw.s[6] = {pe_w1, pe_w1T, 128, 128};
  tw.s[7] = {pe_w2, pe_w2T, 128, 128};
  tw.s[8] = {np_w0, np_w0T, 128, 128};
  tw.s[9] = {np_w1, np_w1T, 128, 128};

  k_front<<<NB_EXT + NB_TW + NB_PIN + NB_AGZ, 256, 0, stream>>>(
      Rr, Rs, recv, tw, state, attrs, action, phys, pin, agg);

  k_enc<<<NREL / 64 + N_PART / 64, 256, 0, stream>>>(
      pin, recv, send, pinst,
      re_w0T, re_b0, re_w1T, re_b1, re_w2T, re_b2,
      pe_w0T, pe_b0, pe_w1T, pe_b1, pe_w2T, pe_b2, RE, PE);

  u16* ecur = PE;
  u16* enext = eA;
  for (int step = 0; step < 3; ++step) {
    k_mgemm32<1, 384><<<NREL / 32, 256, 0, stream>>>(RE, rp_wT, rp_b, nullptr, nullptr,
                                                     ecur, nullptr, recv, send, agg);
    k_mgemm32<2, 256><<<N_PART / 32, 256, 0, stream>>>(PE, pp_wT, pp_b, ecur, enext,
                                                       nullptr, agg, nullptr, nullptr, nullptr);
    ecur = enext;
    enext = (ecur == eA) ? eB : eA;
  }

  k_np<<<32, 256, 0, stream>>>(ecur, np_w0T, np_b0, np_w1T, np_b1,
                               np_w2, np_b2, state, (float*)d_out);
}

// Round 11
// 131.673 us; speedup vs baseline: 1.0049x; 1.0049x over previous
//
#include <hip/hip_runtime.h>

#define N_PART 2048
#define NP_OBJ 2000
#define NREL 16384

typedef unsigned short u16;
typedef __attribute__((ext_vector_type(8))) short bf16x8;
typedef __attribute__((ext_vector_type(4))) float f32x4;

__device__ __forceinline__ int clampi(int v) {
  return v < 0 ? 0 : (v >= N_PART ? N_PART - 1 : v);
}
__device__ __forceinline__ u16 f2b(float f) {
  union { float f; unsigned int u; } v; v.f = f;
  return (u16)((v.u + 0x7fffu + ((v.u >> 16) & 1u)) >> 16);  // RNE
}
__device__ __forceinline__ float b2f(u16 u) {
  union { unsigned int i; float f; } v; v.i = ((unsigned int)u) << 16; return v.f;
}

struct TWSeg { const float* src; u16* dst; int K; int Kp; };
struct TW10 { TWSeg s[10]; };

// ---- front kernel: extract via global_load_lds DMA + weight transpose +
//      pinputs + agg zero.  Extract: 8 rows/block (64 KB LDS), 2 blocks/CU.
#define NB_EXT 4096   /* 8 rows each -> 32768 rows */
#define NB_TW  320
#define NB_PIN 8
#define NB_AGZ 8
__global__ __launch_bounds__(256) void k_front(
    const float* __restrict__ Rr, const float* __restrict__ Rs,
    int* __restrict__ recv /* send = recv + NREL */, TW10 tw,
    const float* __restrict__ state, const float* __restrict__ attrs,
    const float* __restrict__ action, const float* __restrict__ phys,
    float* __restrict__ pin, float* __restrict__ agg) {
  __shared__ unsigned int buf[8 * 2048];   // 64 KB
  int b = blockIdx.x;
  int tid = threadIdx.x;
  if (b < NB_EXT) {
    int wv = tid >> 6, lane = tid & 63;
    int wid0 = b * 8;
    // each wave DMA-stages 2 rows (16 x 1KB global_load_lds, fire-and-forget)
#pragma unroll
    for (int rr = 0; rr < 2; ++rr) {
      int r = wv * 2 + rr;
      int wid = wid0 + r;
      bool second = wid >= NREL;
      int row = second ? wid - NREL : wid;
      const float* src = (second ? Rs : Rr) + (size_t)row * N_PART + lane * 4;
#pragma unroll
      for (int j = 0; j < 8; ++j) {
        __builtin_amdgcn_global_load_lds(
            (const __attribute__((address_space(1))) void*)(src + j * 256),
            (__attribute__((address_space(3))) void*)&buf[r * 2048 + j * 256],
            16, 0, 0);
      }
    }
    __syncthreads();  // drains vmcnt (DMA complete)
    // scan: thread t scans row t>>5; lane sub=t&31 reads words j*32+sub
    // (banks 0..31, conflict-free), branchless col select
    int r = tid >> 5, sub = tid & 31;
    const unsigned int* rowp = &buf[r * 2048];
    int col = 0;
#pragma unroll
    for (int j = 0; j < 64; ++j) {
      unsigned int v = rowp[j * 32 + sub];
      if (v) col = j * 32 + sub;
    }
#pragma unroll
    for (int s = 16; s; s >>= 1) col |= __shfl_xor(col, s, 32);
    if (sub == 0) {
      int wid = wid0 + r;
      bool second = wid >= NREL;
      int row = second ? wid - NREL : wid;
      recv[(second ? NREL : 0) + row] = col;
    }
  } else if (b < NB_EXT + NB_TW) {
    // ---- weight transpose + bf16 convert: W[K][128] -> WT[128][Kp] ----
    int b2 = b - NB_EXT;
    TWSeg sg = tw.s[b2 >> 5];
    int n = (b2 & 31) * 4 + (tid >> 6);
    int k0 = tid & 63;
    for (int k = k0; k < sg.Kp; k += 64) {
      float v = (k < sg.K) ? sg.src[(size_t)k * 128 + n] : 0.f;
      sg.dst[(size_t)n * sg.Kp + k] = f2b(v);
    }
  } else if (b < NB_EXT + NB_TW + NB_PIN) {
    // ---- p_inputs [2048][16] ----
    int i = (b - NB_EXT - NB_TW) * 256 + tid;
    float s0[3], s1[3], s2[3];
#pragma unroll
    for (int d = 0; d < 3; ++d) {
      s0[d] = state[(0 * N_PART + i) * 3 + d];
      s1[d] = state[(1 * N_PART + i) * 3 + d];
      s2[d] = state[(2 * N_PART + i) * 3 + d];
    }
    float* o = pin + (size_t)i * 16;
    o[0] = attrs[i * 2 + 0];
    o[1] = attrs[i * 2 + 1];
#pragma unroll
    for (int d = 0; d < 3; ++d) {
      o[2 + d] = s1[d] - s0[d];
      o[5 + d] = s2[d] - s1[d];
      o[8 + d] = s2[d];
    }
    o[11] = (i < NP_OBJ) ? phys[i] : 0.f;
#pragma unroll
    for (int d = 0; d < 3; ++d) o[12 + d] = action[i * 3 + d];
    o[15] = 0.f;
  } else {
    // ---- zero agg (N_PART*128 floats = 65536 float4) ----
    int b3 = b - NB_EXT - NB_TW - NB_PIN;
    float4* a4 = (float4*)agg;
    float4 z = make_float4(0.f, 0.f, 0.f, 0.f);
#pragma unroll
    for (int j = 0; j < 32; ++j) a4[(size_t)j * 2048 + b3 * 256 + tid] = z;
  }
}

// ---- one MFMA MLP layer on a 64-row LDS-resident tile --------------------
template <int K, bool TOGLOBAL>
__device__ __forceinline__ void re_layer(
    const u16 (*hIn)[136], u16 (*hOut)[136], u16 (*wt)[72],
    const u16* __restrict__ WTg, const float* __restrict__ bias,
    u16* __restrict__ gout, int row0, int tid) {
  int lane = tid & 63, w = tid >> 6;
  int wr0 = (w >> 1) * 32, wc0 = (w & 1) * 64;
  f32x4 acc[2][4] = {};
  for (int kc = 0; kc < K; kc += 64) {
    __syncthreads();
#pragma unroll
    for (int i = 0; i < 4; ++i) {
      int idx = i * 256 + tid;
      int n = idx >> 3, kl8 = (idx & 7) * 8;
      *(bf16x8*)&wt[n][kl8] = *(const bf16x8*)&WTg[(size_t)n * K + kc + kl8];
    }
    __syncthreads();
#pragma unroll
    for (int ks = 0; ks < 64; ks += 32) {
      bf16x8 a0 = *(const bf16x8*)&hIn[wr0 + (lane & 15)][kc + ks + 8 * (lane >> 4)];
      bf16x8 a1 = *(const bf16x8*)&hIn[wr0 + 16 + (lane & 15)][kc + ks + 8 * (lane >> 4)];
#pragma unroll
      for (int ct = 0; ct < 4; ++ct) {
        bf16x8 bq = *(const bf16x8*)&wt[wc0 + ct * 16 + (lane & 15)][ks + 8 * (lane >> 4)];
        acc[0][ct] = __builtin_amdgcn_mfma_f32_16x16x32_bf16(a0, bq, acc[0][ct], 0, 0, 0);
        acc[1][ct] = __builtin_amdgcn_mfma_f32_16x16x32_bf16(a1, bq, acc[1][ct], 0, 0, 0);
      }
    }
  }
  __syncthreads();
#pragma unroll
  for (int ct = 0; ct < 4; ++ct) {
    int col = wc0 + ct * 16 + (lane & 15);
    float bb = bias[col];
#pragma unroll
    for (int rt = 0; rt < 2; ++rt) {
#pragma unroll
      for (int rg = 0; rg < 4; ++rg) {
        int rl = wr0 + rt * 16 + (lane >> 4) * 4 + rg;
        float v = fmaxf(acc[rt][ct][rg] + bb, 0.f);
        if (TOGLOBAL) gout[(size_t)(row0 + rl) * 128 + col] = f2b(v);
        else          hOut[rl][col] = f2b(v);
      }
    }
  }
}

// ---- fused encoders: blocks [0,256) relation rows, [256,288) particle rows
__global__ __launch_bounds__(256) void k_enc(
    const float* __restrict__ pin, const int* __restrict__ recv,
    const int* __restrict__ send, const float* __restrict__ pinst,
    const u16* __restrict__ rw0T, const float* __restrict__ rb0,
    const u16* __restrict__ rw1T, const float* __restrict__ rb1,
    const u16* __restrict__ rw2T, const float* __restrict__ rb2,
    const u16* __restrict__ pw0T, const float* __restrict__ pb0,
    const u16* __restrict__ pw1T, const float* __restrict__ pb1,
    const u16* __restrict__ pw2T, const float* __restrict__ pb2,
    u16* __restrict__ RE, u16* __restrict__ PE) {
  __shared__ u16 hA[64][136];
  __shared__ u16 hB[64][136];
  __shared__ u16 wt[128][72];
  int tid = threadIdx.x;
  bool isRel = blockIdx.x < NREL / 64;
  int row0 = (isRel ? blockIdx.x : blockIdx.x - NREL / 64) * 64;
  if (isRel) {
#pragma unroll
    for (int i = 0; i < 16; ++i) {
      int idx = i * 256 + tid;
      int r = idx >> 6, c = idx & 63;
      int e = row0 + r;
      int rr = clampi(recv[e]), ss = clampi(send[e]);
      const float* pr = pin + (size_t)rr * 16;
      const float* ps = pin + (size_t)ss * 16;
      float v = 0.f;
      if (c < 15) v = pr[c];
      else if (c < 30) v = ps[c - 15];
      else if (c < 32) v = pr[c - 30];
      else if (c < 34) v = ps[c - 32];
      else if (c == 34) {
        float gd = 0.f;
#pragma unroll
        for (int j = 0; j < 8; ++j) {
          float gr = (rr < NP_OBJ) ? pinst[rr * 8 + j] : 0.f;
          float gs = (ss < NP_OBJ) ? pinst[ss * 8 + j] : 0.f;
          gd += fabsf(gr - gs);
        }
        v = gd;
      } else if (c < 44) {
        v = pr[2 + c - 35] - ps[2 + c - 35];
      }
      hA[r][c] = f2b(v);
    }
  } else {
#pragma unroll
    for (int i = 0; i < 16; ++i) {
      int idx = i * 256 + tid;
      int r = idx >> 6, c = idx & 63;
      float v = (c < 16) ? pin[(size_t)(row0 + r) * 16 + c] : 0.f;
      hA[r][c] = f2b(v);
    }
  }
  const u16* w0T = isRel ? rw0T : pw0T;  const float* b0 = isRel ? rb0 : pb0;
  const u16* w1T = isRel ? rw1T : pw1T;  const float* b1 = isRel ? rb1 : pb1;
  const u16* w2T = isRel ? rw2T : pw2T;  const float* b2 = isRel ? rb2 : pb2;
  u16* gout = isRel ? RE : PE;
  re_layer<64, false>(hA, hB, wt, w0T, b0, nullptr, row0, tid);
  re_layer<128, false>(hB, hA, wt, w1T, b1, nullptr, row0, tid);
  re_layer<128, true>(hA, hB, wt, w2T, b2, gout, row0, tid);
}

// ---- MFMA GEMM, 32-row tiles ---------------------------------------------
// MODE 1 (KTOT=384): A row e = [RE[e] | eff[recv[e]] | eff[send[e]]];
//          epilogue relu + atomic scatter-add into aggOut[recv[e]].
// MODE 2 (KTOT=256): A row i = [PE[i] | aggIn[i](f32)]; stager zeroes aggIn
//          after read (self-clean); epilogue relu(+bias+resid)->bf16.
template <int MODE, int KTOT>
__global__ __launch_bounds__(256) void k_mgemm32(
    const u16* __restrict__ A, const u16* __restrict__ WT,
    const float* __restrict__ bias,
    const u16* __restrict__ resid, u16* __restrict__ out,
    const u16* __restrict__ eff, float* __restrict__ aggIn,
    const int* __restrict__ recv, const int* __restrict__ send,
    float* __restrict__ aggOut) {
  __shared__ u16 a_lds[32][72];
  __shared__ u16 wt_lds[128][72];
  int tid = threadIdx.x;
  int lane = tid & 63, w = tid >> 6;
  int wr0 = (w >> 1) * 16, wc0 = (w & 1) * 64;
  int row0 = blockIdx.x * 32;
  f32x4 acc[4] = {};
  for (int kc = 0; kc < KTOT; kc += 64) {
    __syncthreads();
    {
      int r = tid >> 3, kl8 = (tid & 7) * 8;
      int grow = row0 + r;
      if (MODE == 1) {
        const u16* src;
        if (kc < 128)      src = A + (size_t)grow * 128 + kc;
        else if (kc < 256) src = eff + (size_t)clampi(recv[grow]) * 128 + (kc - 128);
        else               src = eff + (size_t)clampi(send[grow]) * 128 + (kc - 256);
        *(bf16x8*)&a_lds[r][kl8] = *(const bf16x8*)&src[kl8];
      } else {
        if (kc < 128) {
          *(bf16x8*)&a_lds[r][kl8] = *(const bf16x8*)&A[(size_t)grow * 128 + kc + kl8];
        } else {
          float* fs = aggIn + (size_t)grow * 128 + (kc - 128) + kl8;
          float4 v0 = *(const float4*)&fs[0];
          float4 v1 = *(const float4*)&fs[4];
          bf16x8 t;
          t[0] = (short)f2b(v0.x); t[1] = (short)f2b(v0.y);
          t[2] = (short)f2b(v0.z); t[3] = (short)f2b(v0.w);
          t[4] = (short)f2b(v1.x); t[5] = (short)f2b(v1.y);
          t[6] = (short)f2b(v1.z); t[7] = (short)f2b(v1.w);
          *(bf16x8*)&a_lds[r][kl8] = t;
          float4 z = make_float4(0.f, 0.f, 0.f, 0.f);
          *(float4*)&fs[0] = z;  // self-clean agg for next step
          *(float4*)&fs[4] = z;
        }
      }
    }
#pragma unroll
    for (int i = 0; i < 4; ++i) {
      int idx = i * 256 + tid;
      int n = idx >> 3, kl8 = (idx & 7) * 8;
      *(bf16x8*)&wt_lds[n][kl8] = *(const bf16x8*)&WT[(size_t)n * KTOT + kc + kl8];
    }
    __syncthreads();
#pragma unroll
    for (int ks = 0; ks < 64; ks += 32) {
      bf16x8 a0 = *(const bf16x8*)&a_lds[wr0 + (lane & 15)][ks + 8 * (lane >> 4)];
#pragma unroll
      for (int ct = 0; ct < 4; ++ct) {
        bf16x8 bq = *(const bf16x8*)&wt_lds[wc0 + ct * 16 + (lane & 15)][ks + 8 * (lane >> 4)];
        acc[ct] = __builtin_amdgcn_mfma_f32_16x16x32_bf16(a0, bq, acc[ct], 0, 0, 0);
      }
    }
  }
  int rbase = row0 + wr0 + (lane >> 4) * 4;
  int dst[4];
#pragma unroll
  for (int rg = 0; rg < 4; ++rg)
    dst[rg] = (MODE == 1) ? clampi(recv[rbase + rg]) : 0;
#pragma unroll
  for (int ct = 0; ct < 4; ++ct) {
    int col = wc0 + ct * 16 + (lane & 15);
    float bb = bias[col];
#pragma unroll
    for (int rg = 0; rg < 4; ++rg) {
      int row = rbase + rg;
      float v = acc[ct][rg] + bb;
      if (MODE == 1) {
        v = fmaxf(v, 0.f);
        atomicAdd(&aggOut[(size_t)dst[rg] * 128 + col], v);
      } else {
        v += b2f(resid[(size_t)row * 128 + col]);
        v = fmaxf(v, 0.f);
        out[(size_t)row * 128 + col] = f2b(v);
      }
    }
  }
}

// ---- fused predictor: 2 MFMA layers + 3-col GEMV + clip + outputs --------
__global__ __launch_bounds__(256) void k_np(
    const u16* __restrict__ eff,
    const u16* __restrict__ w0T, const float* __restrict__ b0,
    const u16* __restrict__ w1T, const float* __restrict__ b1,
    const float* __restrict__ w2, const float* __restrict__ b2,
    const float* __restrict__ state, float* __restrict__ out) {
  __shared__ u16 hA[64][136];
  __shared__ u16 hB[64][136];
  __shared__ u16 wt[128][72];
  __shared__ float sw2[384];
  int tid = threadIdx.x;
  int row0 = blockIdx.x * 64;
#pragma unroll
  for (int i = 0; i < 4; ++i) {
    int idx = i * 256 + tid;
    int r = idx >> 4, kl8 = (idx & 15) * 8;
    *(bf16x8*)&hA[r][kl8] = *(const bf16x8*)&eff[(size_t)(row0 + r) * 128 + kl8];
  }
  for (int j = tid; j < 384; j += 256) sw2[j] = w2[j];
  re_layer<128, false>(hA, hB, wt, w0T, b0, nullptr, row0, tid);
  re_layer<128, false>(hB, hA, wt, w1T, b1, nullptr, row0, tid);
  __syncthreads();
  int r = tid >> 2, d = tid & 3;
  if (d < 3) {
    int row = row0 + r;
    if (row < NP_OBJ) {
      float acc = b2[d];
#pragma unroll 8
      for (int k = 0; k < 128; ++k) acc += b2f(hA[r][k]) * sw2[k * 3 + d];
      float cl = fminf(fmaxf(acc, -100.f), 100.f);
      out[row * 3 + d] = state[(size_t)(2 * N_PART + row) * 3 + d] + cl;
      out[NP_OBJ * 3 + row * 3 + d] = acc;
    }
  }
}

extern "C" void kernel_launch(void* const* d_in, const int* in_sizes, int n_in,
                              void* d_out, int out_size, void* d_ws, size_t ws_size,
                              hipStream_t stream) {
  const float* state  = (const float*)d_in[0];
  const float* attrs  = (const float*)d_in[1];
  const float* Rr     = (const float*)d_in[2];
  const float* Rs     = (const float*)d_in[3];
  const float* pinst  = (const float*)d_in[4];
  const float* action = (const float*)d_in[5];
  const float* phys   = (const float*)d_in[6];
  const float* pe_w0 = (const float*)d_in[7];  const float* pe_b0 = (const float*)d_in[8];
  const float* pe_w1 = (const float*)d_in[9];  const float* pe_b1 = (const float*)d_in[10];
  const float* pe_w2 = (const float*)d_in[11]; const float* pe_b2 = (const float*)d_in[12];
  const float* re_w0 = (const float*)d_in[13]; const float* re_b0 = (const float*)d_in[14];
  const float* re_w1 = (const float*)d_in[15]; const float* re_b1 = (const float*)d_in[16];
  const float* re_w2 = (const float*)d_in[17]; const float* re_b2 = (const float*)d_in[18];
  const float* pp_w  = (const float*)d_in[19]; const float* pp_b  = (const float*)d_in[20];
  const float* rp_w  = (const float*)d_in[21]; const float* rp_b  = (const float*)d_in[22];
  const float* np_w0 = (const float*)d_in[23]; const float* np_b0 = (const float*)d_in[24];
  const float* np_w1 = (const float*)d_in[25]; const float* np_b1 = (const float*)d_in[26];
  const float* np_w2 = (const float*)d_in[27]; const float* np_b2 = (const float*)d_in[28];

  char* ws = (char*)d_ws;
  size_t off = 0;
  auto alloc = [&](size_t b) { size_t o = off; off += (b + 255) & ~(size_t)255; return o; };
  int* recv = (int*)(ws + alloc(2 * NREL * 4));  // send follows recv
  int* send = recv + NREL;
  float* pin = (float*)(ws + alloc((size_t)N_PART * 16 * 4));
  u16* PE  = (u16*)(ws + alloc((size_t)N_PART * 128 * 2));
  u16* RE  = (u16*)(ws + alloc((size_t)NREL * 128 * 2));
  float* agg = (float*)(ws + alloc((size_t)N_PART * 128 * 4));
  u16* eA  = (u16*)(ws + alloc((size_t)N_PART * 128 * 2));
  u16* eB  = (u16*)(ws + alloc((size_t)N_PART * 128 * 2));
  u16* re_w0T = (u16*)(ws + alloc(128 * 64 * 2));
  u16* re_w1T = (u16*)(ws + alloc(128 * 128 * 2));
  u16* re_w2T = (u16*)(ws + alloc(128 * 128 * 2));
  u16* rp_wT  = (u16*)(ws + alloc(128 * 384 * 2));
  u16* pp_wT  = (u16*)(ws + alloc(128 * 256 * 2));
  u16* pe_w0T = (u16*)(ws + alloc(128 * 64 * 2));
  u16* pe_w1T = (u16*)(ws + alloc(128 * 128 * 2));
  u16* pe_w2T = (u16*)(ws + alloc(128 * 128 * 2));
  u16* np_w0T = (u16*)(ws + alloc(128 * 128 * 2));
  u16* np_w1T = (u16*)(ws + alloc(128 * 128 * 2));
  if (off > ws_size) return;  // diagnostic guard

  TW10 tw;
  tw.s[0] = {re_w0, re_w0T, 44, 64};
  tw.s[1] = {re_w1, re_w1T, 128, 128};
  tw.s[2] = {re_w2, re_w2T, 128, 128};
  tw.s[3] = {rp_w,  rp_wT,  384, 384};
  tw.s[4] = {pp_w,  pp_wT,  256, 256};
  tw.s[5] = {pe_w0, pe_w0T, 15, 64};
  tw.s[6] = {pe_w1, pe_w1T, 128, 128};
  tw.s[7] = {pe_w2, pe_w2T, 128, 128};
  tw.s[8] = {np_w0, np_w0T, 128, 128};
  tw.s[9] = {np_w1, np_w1T, 128, 128};

  k_front<<<NB_EXT + NB_TW + NB_PIN + NB_AGZ, 256, 0, stream>>>(
      Rr, Rs, recv, tw, state, attrs, action, phys, pin, agg);

  k_enc<<<NREL / 64 + N_PART / 64, 256, 0, stream>>>(
      pin, recv, send, pinst,
      re_w0T, re_b0, re_w1T, re_b1, re_w2T, re_b2,
      pe_w0T, pe_b0, pe_w1T, pe_b1, pe_w2T, pe_b2, RE, PE);

  u16* ecur = PE;
  u16* enext = eA;
  for (int step = 0; step < 3; ++step) {
    k_mgemm32<1, 384><<<NREL / 32, 256, 0, stream>>>(RE, rp_wT, rp_b, nullptr, nullptr,
                                                     ecur, nullptr, recv, send, agg);
    k_mgemm32<2, 256><<<N_PART / 32, 256, 0, stream>>>(PE, pp_wT, pp_b, ecur, enext,
                                                       nullptr, agg, nullptr, nullptr, nullptr);
    ecur = enext;
    enext = (ecur == eA) ? eB : eA;
  }

  k_np<<<32, 256, 0, stream>>>(ecur, np_w0T, np_b0, np_w1T, np_b1,
                               np_w2, np_b2, state, (float*)d_out);
}

// Round 13
// 115.465 us; speedup vs baseline: 1.1460x; 1.1404x over previous
//
#include <hip/hip_runtime.h>

#define N_PART 2048
#define NP_OBJ 2000
#define NREL 16384

typedef unsigned short u16;
typedef __attribute__((ext_vector_type(8))) short bf16x8;
typedef __attribute__((ext_vector_type(4))) float f32x4;
typedef __attribute__((ext_vector_type(4))) unsigned int u32x4;

__device__ __forceinline__ int clampi(int v) {
  return v < 0 ? 0 : (v >= N_PART ? N_PART - 1 : v);
}
__device__ __forceinline__ u16 f2b(float f) {
  union { float f; unsigned int u; } v; v.f = f;
  return (u16)((v.u + 0x7fffu + ((v.u >> 16) & 1u)) >> 16);  // RNE
}
__device__ __forceinline__ float b2f(u16 u) {
  union { unsigned int i; float f; } v; v.i = ((unsigned int)u) << 16; return v.f;
}

struct TWSeg { const float* src; u16* dst; int K; int Kp; };
struct TW10 { TWSeg s[10]; };

// ---- front kernel: early-exit extract + weight transpose + pinputs + agg zero
#define NB_EXT 8192   /* 4 waves/block -> 32768 rows */
#define NB_TW  320
#define NB_PIN 8
#define NB_AGZ 8
__global__ __launch_bounds__(256) void k_front(
    const float* __restrict__ Rr, const float* __restrict__ Rs,
    int* __restrict__ recv /* send = recv + NREL */, TW10 tw,
    const float* __restrict__ state, const float* __restrict__ attrs,
    const float* __restrict__ action, const float* __restrict__ phys,
    float* __restrict__ pin, float* __restrict__ agg) {
  int b = blockIdx.x;
  int tid = threadIdx.x;
  if (b < NB_EXT) {
    // ---- one wave per one-hot row; scan 1KB chunks, wave-uniform early exit.
    // E[bytes] = 56% of row (hit position uniform) -> ~150 MB total vs 268 MB.
    int wid = b * 4 + (tid >> 6);          // 0 .. 2*NREL-1
    int lane = tid & 63;
    bool second = wid >= NREL;
    int row = second ? wid - NREL : wid;
    const u32x4* p = (const u32x4*)((second ? Rs : Rr) + (size_t)row * N_PART) + lane;
    int col = -1;
#pragma unroll
    for (int k = 0; k < 8; ++k) {
      u32x4 v = p[k * 64];
      int base = (k * 64 + lane) * 4;
      int c = -1;
      if (v.x) c = base;            // branchless v_cndmask chain
      if (v.y) c = base + 1;
      if (v.z) c = base + 2;
      if (v.w) c = base + 3;
#pragma unroll
      for (int s = 32; s; s >>= 1) {
        int t = __shfl_xor(c, s);
        c = (t > c) ? t : c;        // wave max-reduce
      }
      if (c >= 0) { col = c; break; }  // wave-uniform break
    }
    if (lane == 0) recv[(second ? NREL : 0) + row] = col;
  } else if (b < NB_EXT + NB_TW) {
    // ---- weight transpose + bf16 convert: W[K][128] -> WT[128][Kp] ----
    int b2 = b - NB_EXT;
    TWSeg sg = tw.s[b2 >> 5];
    int n = (b2 & 31) * 4 + (tid >> 6);
    int k0 = tid & 63;
    for (int k = k0; k < sg.Kp; k += 64) {
      float v = (k < sg.K) ? sg.src[(size_t)k * 128 + n] : 0.f;
      sg.dst[(size_t)n * sg.Kp + k] = f2b(v);
    }
  } else if (b < NB_EXT + NB_TW + NB_PIN) {
    // ---- p_inputs [2048][16] ----
    int i = (b - NB_EXT - NB_TW) * 256 + tid;
    float s0[3], s1[3], s2[3];
#pragma unroll
    for (int d = 0; d < 3; ++d) {
      s0[d] = state[(0 * N_PART + i) * 3 + d];
      s1[d] = state[(1 * N_PART + i) * 3 + d];
      s2[d] = state[(2 * N_PART + i) * 3 + d];
    }
    float* o = pin + (size_t)i * 16;
    o[0] = attrs[i * 2 + 0];
    o[1] = attrs[i * 2 + 1];
#pragma unroll
    for (int d = 0; d < 3; ++d) {
      o[2 + d] = s1[d] - s0[d];
      o[5 + d] = s2[d] - s1[d];
      o[8 + d] = s2[d];
    }
    o[11] = (i < NP_OBJ) ? phys[i] : 0.f;
#pragma unroll
    for (int d = 0; d < 3; ++d) o[12 + d] = action[i * 3 + d];
    o[15] = 0.f;
  } else {
    // ---- zero agg (N_PART*128 floats = 65536 float4) ----
    int b3 = b - NB_EXT - NB_TW - NB_PIN;
    float4* a4 = (float4*)agg;
    float4 z = make_float4(0.f, 0.f, 0.f, 0.f);
#pragma unroll
    for (int j = 0; j < 32; ++j) a4[(size_t)j * 2048 + b3 * 256 + tid] = z;
  }
}

// ---- one MFMA MLP layer on a 64-row LDS-resident tile --------------------
template <int K, bool TOGLOBAL>
__device__ __forceinline__ void re_layer(
    const u16 (*hIn)[136], u16 (*hOut)[136], u16 (*wt)[72],
    const u16* __restrict__ WTg, const float* __restrict__ bias,
    u16* __restrict__ gout, int row0, int tid) {
  int lane = tid & 63, w = tid >> 6;
  int wr0 = (w >> 1) * 32, wc0 = (w & 1) * 64;
  f32x4 acc[2][4] = {};
  for (int kc = 0; kc < K; kc += 64) {
    __syncthreads();
#pragma unroll
    for (int i = 0; i < 4; ++i) {
      int idx = i * 256 + tid;
      int n = idx >> 3, kl8 = (idx & 7) * 8;
      *(bf16x8*)&wt[n][kl8] = *(const bf16x8*)&WTg[(size_t)n * K + kc + kl8];
    }
    __syncthreads();
#pragma unroll
    for (int ks = 0; ks < 64; ks += 32) {
      bf16x8 a0 = *(const bf16x8*)&hIn[wr0 + (lane & 15)][kc + ks + 8 * (lane >> 4)];
      bf16x8 a1 = *(const bf16x8*)&hIn[wr0 + 16 + (lane & 15)][kc + ks + 8 * (lane >> 4)];
#pragma unroll
      for (int ct = 0; ct < 4; ++ct) {
        bf16x8 bq = *(const bf16x8*)&wt[wc0 + ct * 16 + (lane & 15)][ks + 8 * (lane >> 4)];
        acc[0][ct] = __builtin_amdgcn_mfma_f32_16x16x32_bf16(a0, bq, acc[0][ct], 0, 0, 0);
        acc[1][ct] = __builtin_amdgcn_mfma_f32_16x16x32_bf16(a1, bq, acc[1][ct], 0, 0, 0);
      }
    }
  }
  __syncthreads();
#pragma unroll
  for (int ct = 0; ct < 4; ++ct) {
    int col = wc0 + ct * 16 + (lane & 15);
    float bb = bias[col];
#pragma unroll
    for (int rt = 0; rt < 2; ++rt) {
#pragma unroll
      for (int rg = 0; rg < 4; ++rg) {
        int rl = wr0 + rt * 16 + (lane >> 4) * 4 + rg;
        float v = fmaxf(acc[rt][ct][rg] + bb, 0.f);
        if (TOGLOBAL) gout[(size_t)(row0 + rl) * 128 + col] = f2b(v);
        else          hOut[rl][col] = f2b(v);
      }
    }
  }
}

// ---- fused encoders: blocks [0,256) relation rows, [256,288) particle rows
__global__ __launch_bounds__(256) void k_enc(
    const float* __restrict__ pin, const int* __restrict__ recv,
    const int* __restrict__ send, const float* __restrict__ pinst,
    const u16* __restrict__ rw0T, const float* __restrict__ rb0,
    const u16* __restrict__ rw1T, const float* __restrict__ rb1,
    const u16* __restrict__ rw2T, const float* __restrict__ rb2,
    const u16* __restrict__ pw0T, const float* __restrict__ pb0,
    const u16* __restrict__ pw1T, const float* __restrict__ pb1,
    const u16* __restrict__ pw2T, const float* __restrict__ pb2,
    u16* __restrict__ RE, u16* __restrict__ PE) {
  __shared__ u16 hA[64][136];
  __shared__ u16 hB[64][136];
  __shared__ u16 wt[128][72];
  int tid = threadIdx.x;
  bool isRel = blockIdx.x < NREL / 64;
  int row0 = (isRel ? blockIdx.x : blockIdx.x - NREL / 64) * 64;
  if (isRel) {
#pragma unroll
    for (int i = 0; i < 16; ++i) {
      int idx = i * 256 + tid;
      int r = idx >> 6, c = idx & 63;
      int e = row0 + r;
      int rr = clampi(recv[e]), ss = clampi(send[e]);
      const float* pr = pin + (size_t)rr * 16;
      const float* ps = pin + (size_t)ss * 16;
      float v = 0.f;
      if (c < 15) v = pr[c];
      else if (c < 30) v = ps[c - 15];
      else if (c < 32) v = pr[c - 30];
      else if (c < 34) v = ps[c - 32];
      else if (c == 34) {
        float gd = 0.f;
#pragma unroll
        for (int j = 0; j < 8; ++j) {
          float gr = (rr < NP_OBJ) ? pinst[rr * 8 + j] : 0.f;
          float gs = (ss < NP_OBJ) ? pinst[ss * 8 + j] : 0.f;
          gd += fabsf(gr - gs);
        }
        v = gd;
      } else if (c < 44) {
        v = pr[2 + c - 35] - ps[2 + c - 35];
      }
      hA[r][c] = f2b(v);
    }
  } else {
#pragma unroll
    for (int i = 0; i < 16; ++i) {
      int idx = i * 256 + tid;
      int r = idx >> 6, c = idx & 63;
      float v = (c < 16) ? pin[(size_t)(row0 + r) * 16 + c] : 0.f;
      hA[r][c] = f2b(v);
    }
  }
  const u16* w0T = isRel ? rw0T : pw0T;  const float* b0 = isRel ? rb0 : pb0;
  const u16* w1T = isRel ? rw1T : pw1T;  const float* b1 = isRel ? rb1 : pb1;
  const u16* w2T = isRel ? rw2T : pw2T;  const float* b2 = isRel ? rb2 : pb2;
  u16* gout = isRel ? RE : PE;
  re_layer<64, false>(hA, hB, wt, w0T, b0, nullptr, row0, tid);
  re_layer<128, false>(hB, hA, wt, w1T, b1, nullptr, row0, tid);
  re_layer<128, true>(hA, hB, wt, w2T, b2, gout, row0, tid);
}

// ---- MFMA GEMM, 32-row tiles ---------------------------------------------
// MODE 1 (KTOT=384): A row e = [RE[e] | eff[recv[e]] | eff[send[e]]];
//          epilogue relu + atomic scatter-add into aggOut[recv[e]].
// MODE 2 (KTOT=256): A row i = [PE[i] | aggIn[i](f32)]; stager zeroes aggIn
//          after read (self-clean); epilogue relu(+bias+resid)->bf16.
template <int MODE, int KTOT>
__global__ __launch_bounds__(256) void k_mgemm32(
    const u16* __restrict__ A, const u16* __restrict__ WT,
    const float* __restrict__ bias,
    const u16* __restrict__ resid, u16* __restrict__ out,
    const u16* __restrict__ eff, float* __restrict__ aggIn,
    const int* __restrict__ recv, const int* __restrict__ send,
    float* __restrict__ aggOut) {
  __shared__ u16 a_lds[32][72];
  __shared__ u16 wt_lds[128][72];
  int tid = threadIdx.x;
  int lane = tid & 63, w = tid >> 6;
  int wr0 = (w >> 1) * 16, wc0 = (w & 1) * 64;
  int row0 = blockIdx.x * 32;
  f32x4 acc[4] = {};
  for (int kc = 0; kc < KTOT; kc += 64) {
    __syncthreads();
    {
      int r = tid >> 3, kl8 = (tid & 7) * 8;
      int grow = row0 + r;
      if (MODE == 1) {
        const u16* src;
        if (kc < 128)      src = A + (size_t)grow * 128 + kc;
        else if (kc < 256) src = eff + (size_t)clampi(recv[grow]) * 128 + (kc - 128);
        else               src = eff + (size_t)clampi(send[grow]) * 128 + (kc - 256);
        *(bf16x8*)&a_lds[r][kl8] = *(const bf16x8*)&src[kl8];
      } else {
        if (kc < 128) {
          *(bf16x8*)&a_lds[r][kl8] = *(const bf16x8*)&A[(size_t)grow * 128 + kc + kl8];
        } else {
          float* fs = aggIn + (size_t)grow * 128 + (kc - 128) + kl8;
          float4 v0 = *(const float4*)&fs[0];
          float4 v1 = *(const float4*)&fs[4];
          bf16x8 t;
          t[0] = (short)f2b(v0.x); t[1] = (short)f2b(v0.y);
          t[2] = (short)f2b(v0.z); t[3] = (short)f2b(v0.w);
          t[4] = (short)f2b(v1.x); t[5] = (short)f2b(v1.y);
          t[6] = (short)f2b(v1.z); t[7] = (short)f2b(v1.w);
          *(bf16x8*)&a_lds[r][kl8] = t;
          float4 z = make_float4(0.f, 0.f, 0.f, 0.f);
          *(float4*)&fs[0] = z;  // self-clean agg for next step
          *(float4*)&fs[4] = z;
        }
      }
    }
#pragma unroll
    for (int i = 0; i < 4; ++i) {
      int idx = i * 256 + tid;
      int n = idx >> 3, kl8 = (idx & 7) * 8;
      *(bf16x8*)&wt_lds[n][kl8] = *(const bf16x8*)&WT[(size_t)n * KTOT + kc + kl8];
    }
    __syncthreads();
#pragma unroll
    for (int ks = 0; ks < 64; ks += 32) {
      bf16x8 a0 = *(const bf16x8*)&a_lds[wr0 + (lane & 15)][ks + 8 * (lane >> 4)];
#pragma unroll
      for (int ct = 0; ct < 4; ++ct) {
        bf16x8 bq = *(const bf16x8*)&wt_lds[wc0 + ct * 16 + (lane & 15)][ks + 8 * (lane >> 4)];
        acc[ct] = __builtin_amdgcn_mfma_f32_16x16x32_bf16(a0, bq, acc[ct], 0, 0, 0);
      }
    }
  }
  int rbase = row0 + wr0 + (lane >> 4) * 4;
  int dst[4];
#pragma unroll
  for (int rg = 0; rg < 4; ++rg)
    dst[rg] = (MODE == 1) ? clampi(recv[rbase + rg]) : 0;
#pragma unroll
  for (int ct = 0; ct < 4; ++ct) {
    int col = wc0 + ct * 16 + (lane & 15);
    float bb = bias[col];
#pragma unroll
    for (int rg = 0; rg < 4; ++rg) {
      int row = rbase + rg;
      float v = acc[ct][rg] + bb;
      if (MODE == 1) {
        v = fmaxf(v, 0.f);
        atomicAdd(&aggOut[(size_t)dst[rg] * 128 + col], v);
      } else {
        v += b2f(resid[(size_t)row * 128 + col]);
        v = fmaxf(v, 0.f);
        out[(size_t)row * 128 + col] = f2b(v);
      }
    }
  }
}

// ---- fused predictor: 2 MFMA layers + 3-col GEMV + clip + outputs --------
__global__ __launch_bounds__(256) void k_np(
    const u16* __restrict__ eff,
    const u16* __restrict__ w0T, const float* __restrict__ b0,
    const u16* __restrict__ w1T, const float* __restrict__ b1,
    const float* __restrict__ w2, const float* __restrict__ b2,
    const float* __restrict__ state, float* __restrict__ out) {
  __shared__ u16 hA[64][136];
  __shared__ u16 hB[64][136];
  __shared__ u16 wt[128][72];
  __shared__ float sw2[384];
  int tid = threadIdx.x;
  int row0 = blockIdx.x * 64;
#pragma unroll
  for (int i = 0; i < 4; ++i) {
    int idx = i * 256 + tid;
    int r = idx >> 4, kl8 = (idx & 15) * 8;
    *(bf16x8*)&hA[r][kl8] = *(const bf16x8*)&eff[(size_t)(row0 + r) * 128 + kl8];
  }
  for (int j = tid; j < 384; j += 256) sw2[j] = w2[j];
  re_layer<128, false>(hA, hB, wt, w0T, b0, nullptr, row0, tid);
  re_layer<128, false>(hB, hA, wt, w1T, b1, nullptr, row0, tid);
  __syncthreads();
  int r = tid >> 2, d = tid & 3;
  if (d < 3) {
    int row = row0 + r;
    if (row < NP_OBJ) {
      float acc = b2[d];
#pragma unroll 8
      for (int k = 0; k < 128; ++k) acc += b2f(hA[r][k]) * sw2[k * 3 + d];
      float cl = fminf(fmaxf(acc, -100.f), 100.f);
      out[row * 3 + d] = state[(size_t)(2 * N_PART + row) * 3 + d] + cl;
      out[NP_OBJ * 3 + row * 3 + d] = acc;
    }
  }
}

extern "C" void kernel_launch(void* const* d_in, const int* in_sizes, int n_in,
                              void* d_out, int out_size, void* d_ws, size_t ws_size,
                              hipStream_t stream) {
  const float* state  = (const float*)d_in[0];
  const float* attrs  = (const float*)d_in[1];
  const float* Rr     = (const float*)d_in[2];
  const float* Rs     = (const float*)d_in[3];
  const float* pinst  = (const float*)d_in[4];
  const float* action = (const float*)d_in[5];
  const float* phys   = (const float*)d_in[6];
  const float* pe_w0 = (const float*)d_in[7];  const float* pe_b0 = (const float*)d_in[8];
  const float* pe_w1 = (const float*)d_in[9];  const float* pe_b1 = (const float*)d_in[10];
  const float* pe_w2 = (const float*)d_in[11]; const float* pe_b2 = (const float*)d_in[12];
  const float* re_w0 = (const float*)d_in[13]; const float* re_b0 = (const float*)d_in[14];
  const float* re_w1 = (const float*)d_in[15]; const float* re_b1 = (const float*)d_in[16];
  const float* re_w2 = (const float*)d_in[17]; const float* re_b2 = (const float*)d_in[18];
  const float* pp_w  = (const float*)d_in[19]; const float* pp_b  = (const float*)d_in[20];
  const float* rp_w  = (const float*)d_in[21]; const float* rp_b  = (const float*)d_in[22];
  const float* np_w0 = (const float*)d_in[23]; const float* np_b0 = (const float*)d_in[24];
  const float* np_w1 = (const float*)d_in[25]; const float* np_b1 = (const float*)d_in[26];
  const float* np_w2 = (const float*)d_in[27]; const float* np_b2 = (const float*)d_in[28];

  char* ws = (char*)d_ws;
  size_t off = 0;
  auto alloc = [&](size_t b) { size_t o = off; off += (b + 255) & ~(size_t)255; return o; };
  int* recv = (int*)(ws + alloc(2 * NREL * 4));  // send follows recv
  int* send = recv + NREL;
  float* pin = (float*)(ws + alloc((size_t)N_PART * 16 * 4));
  u16* PE  = (u16*)(ws + alloc((size_t)N_PART * 128 * 2));
  u16* RE  = (u16*)(ws + alloc((size_t)NREL * 128 * 2));
  float* agg = (float*)(ws + alloc((size_t)N_PART * 128 * 4));
  u16* eA  = (u16*)(ws + alloc((size_t)N_PART * 128 * 2));
  u16* eB  = (u16*)(ws + alloc((size_t)N_PART * 128 * 2));
  u16* re_w0T = (u16*)(ws + alloc(128 * 64 * 2));
  u16* re_w1T = (u16*)(ws + alloc(128 * 128 * 2));
  u16* re_w2T = (u16*)(ws + alloc(128 * 128 * 2));
  u16* rp_wT  = (u16*)(ws + alloc(128 * 384 * 2));
  u16* pp_wT  = (u16*)(ws + alloc(128 * 256 * 2));
  u16* pe_w0T = (u16*)(ws + alloc(128 * 64 * 2));
  u16* pe_w1T = (u16*)(ws + alloc(128 * 128 * 2));
  u16* pe_w2T = (u16*)(ws + alloc(128 * 128 * 2));
  u16* np_w0T = (u16*)(ws + alloc(128 * 128 * 2));
  u16* np_w1T = (u16*)(ws + alloc(128 * 128 * 2));
  if (off > ws_size) return;  // diagnostic guard

  TW10 tw;
  tw.s[0] = {re_w0, re_w0T, 44, 64};
  tw.s[1] = {re_w1, re_w1T, 128, 128};
  tw.s[2] = {re_w2, re_w2T, 128, 128};
  tw.s[3] = {rp_w,  rp_wT,  384, 384};
  tw.s[4] = {pp_w,  pp_wT,  256, 256};
  tw.s[5] = {pe_w0, pe_w0T, 15, 64};
  tw.s[6] = {pe_w1, pe_w1T, 128, 128};
  tw.s[7] = {pe_w2, pe_w2T, 128, 128};
  tw.s[8] = {np_w0, np_w0T, 128, 128};
  tw.s[9] = {np_w1, np_w1T, 128, 128};

  k_front<<<NB_EXT + NB_TW + NB_PIN + NB_AGZ, 256, 0, stream>>>(
      Rr, Rs, recv, tw, state, attrs, action, phys, pin, agg);

  k_enc<<<NREL / 64 + N_PART / 64, 256, 0, stream>>>(
      pin, recv, send, pinst,
      re_w0T, re_b0, re_w1T, re_b1, re_w2T, re_b2,
      pe_w0T, pe_b0, pe_w1T, pe_b1, pe_w2T, pe_b2, RE, PE);

  u16* ecur = PE;
  u16* enext = eA;
  for (int step = 0; step < 3; ++step) {
    k_mgemm32<1, 384><<<NREL / 32, 256, 0, stream>>>(RE, rp_wT, rp_b, nullptr, nullptr,
                                                     ecur, nullptr, recv, send, agg);
    k_mgemm32<2, 256><<<N_PART / 32, 256, 0, stream>>>(PE, pp_wT, pp_b, ecur, enext,
                                                       nullptr, agg, nullptr, nullptr, nullptr);
    ecur = enext;
    enext = (ecur == eA) ? eB : eA;
  }

  k_np<<<32, 256, 0, stream>>>(ecur, np_w0T, np_b0, np_w1T, np_b1,
                               np_w2, np_b2, state, (float*)d_out);
}